// Round 3
// baseline (270.969 us; speedup 1.0000x reference)
//
#include <hip/hip_runtime.h>

#define NVV   778
#define NSEG  16
#define SEGSZ 49
#define GRIDN 32
#define BATCH 128
#define NPTS  (NSEG * SEGSZ)           // 784
#define VOLSZ (GRIDN * GRIDN * GRIDN)  // 32768 floats = 128 KB
#define NVOL  (2 * BATCH * NSEG)       // 4096
#define NBLK  256
#define VPB   (NVOL / NBLK)            // 16 volumes per persistent block

// Persistent blocks: 256 blocks x 1024 threads, one per CU (128 KB LDS).
// Each block processes 16 (pass,b,k) volumes with a register-prefetch
// double buffer: loads for volume v+1 are issued before the taps of
// volume v, so the HBM stream never drains.
__global__ __launch_bounds__(1024) void sample_kernel(
    const float* __restrict__ vertices, const int* __restrict__ seg,
    const float* __restrict__ phiR, const float* __restrict__ phiL,
    float* __restrict__ loss)
{
    __shared__ float vol[VOLSZ];        // 128 KB
    __shared__ float wsum[16];
    __shared__ float sbox[4];           // cx, cy, cz, inv_scale

    const int tid = threadIdx.x;

    // ---- prologue: issue staging loads for volume 0 ----
    float4 stg[8];
    {
        int vid  = blockIdx.x;
        int k    = vid % NSEG;
        int b    = (vid / NSEG) % BATCH;
        int pass = vid / (NSEG * BATCH);
        const float* phi = (pass == 0 ? phiR : phiL) +
                           ((size_t)k * BATCH + b) * VOLSZ;
        #pragma unroll
        for (int i = 0; i < 8; ++i)
            stg[i] = *(const float4*)(phi + ((i * 1024 + tid) << 2));
    }

    for (int it = 0; it < VPB; ++it) {
        int vid  = blockIdx.x + NBLK * it;
        int k    = vid % NSEG;
        int b    = (vid / NSEG) % BATCH;
        int pass = vid / (NSEG * BATCH);
        int srcSide = (pass == 0) ? 1 : 0;   // pass0 samples LEFT vertices
        int boxSide = 1 - srcSide;           // with the OTHER side's boxes
        const float* vsrc = vertices + ((size_t)b * 2 + srcSide) * NVV * 3;
        const float* vbox = vertices + ((size_t)b * 2 + boxSide) * NVV * 3;

        // ---- box compute on wave 0 (current volume) ----
        if (tid < 64) {
            bool act = tid < SEGSZ;
            int vi = act ? seg[k * SEGSZ + tid] : 0;
            const float* v = vbox + (size_t)vi * 3;
            float x = v[0], y = v[1], z = v[2];
            float mnx = act ? x : 1e30f, mxx = act ? x : -1e30f;
            float mny = act ? y : 1e30f, mxy = act ? y : -1e30f;
            float mnz = act ? z : 1e30f, mxz = act ? z : -1e30f;
            #pragma unroll
            for (int m = 32; m; m >>= 1) {
                mnx = fminf(mnx, __shfl_xor(mnx, m));
                mxx = fmaxf(mxx, __shfl_xor(mxx, m));
                mny = fminf(mny, __shfl_xor(mny, m));
                mxy = fmaxf(mxy, __shfl_xor(mxy, m));
                mnz = fminf(mnz, __shfl_xor(mnz, m));
                mxz = fmaxf(mxz, __shfl_xor(mxz, m));
            }
            if (tid == 0) {
                sbox[0] = 0.5f * (mnx + mxx);
                sbox[1] = 0.5f * (mny + mxy);
                sbox[2] = 0.5f * (mnz + mxz);
                float ext = fmaxf(fmaxf(mxx - mnx, mxy - mny), mxz - mnz);
                sbox[3] = 1.0f / (0.55f * ext);   // (1+SCALE)*0.5 * ext
            }
        }

        // ---- commit staged registers to LDS (implicit vmcnt wait) ----
        #pragma unroll
        for (int i = 0; i < 8; ++i)
            *(float4*)&vol[(i * 1024 + tid) << 2] = stg[i];

        __syncthreads();   // (A) vol + sbox ready

        // ---- issue prefetch for NEXT volume (in flight during taps) ----
        if (it + 1 < VPB) {
            int nvid  = blockIdx.x + NBLK * (it + 1);
            int nk    = nvid % NSEG;
            int nb    = (nvid / NSEG) % BATCH;
            int npass = nvid / (NSEG * BATCH);
            const float* phin = (npass == 0 ? phiR : phiL) +
                                ((size_t)nk * BATCH + nb) * VOLSZ;
            #pragma unroll
            for (int i = 0; i < 8; ++i)
                stg[i] = *(const float4*)(phin + ((i * 1024 + tid) << 2));
        }

        // ---- trilinear taps from LDS ----
        float acc = 0.0f;
        if (tid < NPTS) {
            int vi = seg[tid];
            const float* v = vsrc + (size_t)vi * 3;
            float vx = v[0], vy = v[1], vz = v[2];
            float cx = sbox[0], cy = sbox[1], cz = sbox[2], invs = sbox[3];
            float fx = ((vx - cx) * invs + 1.0f) * 15.5f;
            float fy = ((vy - cy) * invs + 1.0f) * 15.5f;
            float fz = ((vz - cz) * invs + 1.0f) * 15.5f;
            if (!(fx <= -1.0f || fx >= 32.0f ||
                  fy <= -1.0f || fy >= 32.0f ||
                  fz <= -1.0f || fz >= 32.0f)) {
                float x0f = floorf(fx), y0f = floorf(fy), z0f = floorf(fz);
                float wx = fx - x0f, wy = fy - y0f, wz = fz - z0f;
                int x0 = (int)x0f, y0 = (int)y0f, z0 = (int)z0f;
                #pragma unroll
                for (int dz = 0; dz < 2; ++dz) {
                    int zz = z0 + dz;
                    if (zz < 0 || zz >= GRIDN) continue;
                    float wwz = dz ? wz : 1.0f - wz;
                    #pragma unroll
                    for (int dy = 0; dy < 2; ++dy) {
                        int yy = y0 + dy;
                        if (yy < 0 || yy >= GRIDN) continue;
                        float wzy = wwz * (dy ? wy : 1.0f - wy);
                        const float* row = vol + zz * (GRIDN * GRIDN) + yy * GRIDN;
                        #pragma unroll
                        for (int dx = 0; dx < 2; ++dx) {
                            int xx = x0 + dx;
                            if (xx < 0 || xx >= GRIDN) continue;
                            acc += wzy * (dx ? wx : 1.0f - wx) * row[xx];
                        }
                    }
                }
            }
        }

        // ---- block reduction ----
        #pragma unroll
        for (int off = 32; off; off >>= 1)
            acc += __shfl_down(acc, off);
        int wid  = tid >> 6;
        int lane = tid & 63;
        if (lane == 0) wsum[wid] = acc;
        __syncthreads();   // (B) wsum ready; everyone done reading vol
        if (tid == 0) {
            float tot = 0.f;
            #pragma unroll
            for (int i = 0; i < 16; ++i) tot += wsum[i];
            atomicAdd(loss + b, tot * 0.25f);
        }
        // next iteration's sync (A) protects vol/wsum reuse
    }
}

extern "C" void kernel_launch(void* const* d_in, const int* in_sizes, int n_in,
                              void* d_out, int out_size, void* d_ws, size_t ws_size,
                              hipStream_t stream) {
    const float* vertices = (const float*)d_in[0];
    const float* phiR     = (const float*)d_in[1];
    const float* phiL     = (const float*)d_in[2];
    const int*   seg      = (const int*)d_in[3];
    float* loss = (float*)d_out;

    hipMemsetAsync(d_out, 0, (size_t)out_size * sizeof(float), stream);

    sample_kernel<<<NBLK, 1024, 0, stream>>>(vertices, seg, phiR, phiL, loss);
}